// Round 1
// baseline (1687.816 us; speedup 1.0000x reference)
//
#include <hip/hip_runtime.h>

#define N_NODES 50000
#define N_EDGES 800000
#define C 128
#define N_GRAPHS 512
#define OUTDIM 5
#define BN_EPS 1e-5f

// ---------------- edge kernel: msg = relu(x[src] + ew*We + be); atomic scatter-add to aggr[dst]
__global__ __launch_bounds__(256) void edge_kernel(
    const float* __restrict__ x, const int* __restrict__ ei,
    const float* __restrict__ ew, const float* __restrict__ We,
    const float* __restrict__ be, float* __restrict__ aggr)
{
    int tid = threadIdx.x;
    int e = blockIdx.x * 4 + (tid >> 6);   // 4 edges per 256-thread block, wave-uniform e
    int lane = tid & 63;
    int c = lane * 2;                      // 64 lanes x 2 channels = 128
    int src = ei[e];
    int dst = ei[N_EDGES + e];
    float w = ew[e];
    float2 xv  = *reinterpret_cast<const float2*>(&x[src * C + c]);
    float2 wev = *reinterpret_cast<const float2*>(&We[c]);
    float2 bev = *reinterpret_cast<const float2*>(&be[c]);
    float m0 = xv.x + w * wev.x + bev.x; m0 = m0 > 0.f ? m0 : 0.f;
    float m1 = xv.y + w * wev.y + bev.y; m1 = m1 > 0.f ? m1 : 0.f;
    float* a = &aggr[(size_t)dst * C + c];
    unsafeAtomicAdd(a, m0);       // hw global_atomic_add_f32 (no CAS loop)
    unsafeAtomicAdd(a + 1, m1);
}

// ---------------- 50000x128 @ 128x128^T GEMM, f32 vector ALU
// MODE 0: h = A + B (x + aggr), out = h@W.T + bias          (pre-BN "t")
// MODE 1: h = relu(A*scale + shift) (BN+ReLU on t), out = relu(h@W.T + bias)  (layer output)
template<int MODE>
__global__ __launch_bounds__(256) void gemm_kernel(
    const float* __restrict__ A, const float* __restrict__ B,
    const float* __restrict__ W,          // [128][128] row-major [j][k]
    const float* __restrict__ bias,
    const float* __restrict__ scale, const float* __restrict__ shift,
    float* __restrict__ out)
{
    __shared__ __align__(16) float ws[128 * 132];  // W^T, padded rows: ws[k*132+j]
    __shared__ __align__(16) float hs[16 * 132];   // h tile, padded
    int tid = threadIdx.x;

    // cooperative transposed load of W (once per block)
    #pragma unroll 4
    for (int i = 0; i < 64; ++i) {
        int idx = tid + i * 256;
        int j = idx >> 7, k = idx & 127;
        ws[k * 132 + j] = W[idx];
    }

    int cg = tid & 15;       // col group
    int r  = tid >> 4;       // row within tile (0..15)
    int c0 = cg * 4;         // cols c0..c0+3 and c0+64..c0+67 (contiguous float4s -> no LDS conflict)

    // hoist bias
    float bia[8];
    #pragma unroll
    for (int i = 0; i < 4; ++i) { bia[i] = bias[c0 + i]; bia[4 + i] = bias[c0 + 64 + i]; }

    const int ntiles = N_NODES / 16;   // 3125 exact
    for (int tile = blockIdx.x; tile < ntiles; tile += gridDim.x) {
        int row0 = tile * 16;
        __syncthreads();   // hs safe to overwrite (and ws ready on first iter)
        #pragma unroll
        for (int i = 0; i < 8; ++i) {
            int idx = tid + i * 256;
            int rr = idx >> 7, cc = idx & 127;
            size_t gi = (size_t)(row0 + rr) * C + cc;
            float v;
            if (MODE == 0) {
                v = A[gi] + B[gi];
            } else {
                v = A[gi] * scale[cc] + shift[cc];
                v = v > 0.f ? v : 0.f;
            }
            hs[rr * 132 + cc] = v;
        }
        __syncthreads();

        float acc[8] = {0.f,0.f,0.f,0.f,0.f,0.f,0.f,0.f};
        #pragma unroll 4
        for (int k = 0; k < 128; k += 4) {
            float4 hv = *reinterpret_cast<const float4*>(&hs[r * 132 + k]);
            #pragma unroll
            for (int kk = 0; kk < 4; ++kk) {
                float h = (&hv.x)[kk];
                float4 w0 = *reinterpret_cast<const float4*>(&ws[(k + kk) * 132 + c0]);
                float4 w1 = *reinterpret_cast<const float4*>(&ws[(k + kk) * 132 + c0 + 64]);
                acc[0] += h * w0.x; acc[1] += h * w0.y; acc[2] += h * w0.z; acc[3] += h * w0.w;
                acc[4] += h * w1.x; acc[5] += h * w1.y; acc[6] += h * w1.z; acc[7] += h * w1.w;
            }
        }

        float4 o0, o1;
        o0.x = acc[0] + bia[0]; o0.y = acc[1] + bia[1]; o0.z = acc[2] + bia[2]; o0.w = acc[3] + bia[3];
        o1.x = acc[4] + bia[4]; o1.y = acc[5] + bia[5]; o1.z = acc[6] + bia[6]; o1.w = acc[7] + bia[7];
        if (MODE == 1) {
            o0.x = o0.x > 0.f ? o0.x : 0.f; o0.y = o0.y > 0.f ? o0.y : 0.f;
            o0.z = o0.z > 0.f ? o0.z : 0.f; o0.w = o0.w > 0.f ? o0.w : 0.f;
            o1.x = o1.x > 0.f ? o1.x : 0.f; o1.y = o1.y > 0.f ? o1.y : 0.f;
            o1.z = o1.z > 0.f ? o1.z : 0.f; o1.w = o1.w > 0.f ? o1.w : 0.f;
        }
        size_t ro = (size_t)(row0 + r) * C;
        *reinterpret_cast<float4*>(&out[ro + c0])      = o0;
        *reinterpret_cast<float4*>(&out[ro + c0 + 64]) = o1;
    }
}

// ---------------- column sums / sumsq over t for BatchNorm
__global__ __launch_bounds__(256) void stats_kernel(const float* __restrict__ t,
                                                    float* __restrict__ gsum, float* __restrict__ gsq)
{
    int tid = threadIdx.x;
    int c = tid & 127;
    int half = tid >> 7;
    float s = 0.f, q = 0.f;
    for (int n = blockIdx.x * 2 + half; n < N_NODES; n += gridDim.x * 2) {
        float v = t[(size_t)n * C + c];
        s += v; q += v * v;
    }
    __shared__ float ls[256];
    ls[tid] = s; __syncthreads();
    if (tid < 128) unsafeAtomicAdd(&gsum[tid], ls[tid] + ls[tid + 128]);
    __syncthreads();
    ls[tid] = q; __syncthreads();
    if (tid < 128) unsafeAtomicAdd(&gsq[tid], ls[tid] + ls[tid + 128]);
}

__global__ void bnfin_kernel(const float* __restrict__ gsum, const float* __restrict__ gsq,
                             const float* __restrict__ g, const float* __restrict__ bt,
                             float* __restrict__ scale, float* __restrict__ shift)
{
    int c = threadIdx.x;
    float mu  = gsum[c] * (1.f / N_NODES);
    float var = gsq[c] * (1.f / N_NODES) - mu * mu;
    float rs  = rsqrtf(var + BN_EPS);
    float sc  = rs * g[c];
    scale[c] = sc;
    shift[c] = bt[c] - mu * sc;
}

// ---------------- segment_max pool (values >= 0 after relu -> int-reinterpret atomicMax on zeroed buf)
__global__ __launch_bounds__(256) void pool_kernel(const float* __restrict__ x,
                                                   const int* __restrict__ batch,
                                                   float* __restrict__ pooled)
{
    int idx = blockIdx.x * 256 + threadIdx.x;   // N_NODES*128 exact
    int n = idx >> 7, c = idx & 127;
    int g = batch[n];
    float v = x[idx];
    atomicMax(reinterpret_cast<int*>(&pooled[(size_t)g * C + c]), __float_as_int(v));
}

// ---------------- final linear: out[g][o] = pooled[g] . lin_w[o] + lin_b[o]
__global__ __launch_bounds__(64) void final_kernel(const float* __restrict__ pooled,
                                                   const float* __restrict__ lw,
                                                   const float* __restrict__ lb,
                                                   float* __restrict__ out)
{
    int gph = blockIdx.x;
    int lane = threadIdx.x;
    float v0 = pooled[(size_t)gph * C + lane];
    float v1 = pooled[(size_t)gph * C + lane + 64];
    for (int o = 0; o < OUTDIM; ++o) {
        float p = v0 * lw[o * C + lane] + v1 * lw[o * C + lane + 64];
        #pragma unroll
        for (int off = 32; off > 0; off >>= 1) p += __shfl_down(p, off);
        if (lane == 0) out[gph * OUTDIM + o] = p + lb[o];
    }
}

extern "C" void kernel_launch(void* const* d_in, const int* in_sizes, int n_in,
                              void* d_out, int out_size, void* d_ws, size_t ws_size,
                              hipStream_t stream)
{
    const float* x0   = (const float*)d_in[0];
    const int*   ei   = (const int*)  d_in[1];
    const float* ew   = (const float*)d_in[2];
    const int*   batch= (const int*)  d_in[3];
    const float* We0  = (const float*)d_in[4];
    const float* be0  = (const float*)d_in[5];
    const float* W1_0 = (const float*)d_in[6];
    const float* b1_0 = (const float*)d_in[7];
    const float* g0   = (const float*)d_in[8];
    const float* bt0  = (const float*)d_in[9];
    const float* W2_0 = (const float*)d_in[10];
    const float* b2_0 = (const float*)d_in[11];
    const float* We1  = (const float*)d_in[12];
    const float* be1  = (const float*)d_in[13];
    const float* W1_1 = (const float*)d_in[14];
    const float* b1_1 = (const float*)d_in[15];
    const float* g1   = (const float*)d_in[16];
    const float* bt1  = (const float*)d_in[17];
    const float* W2_1 = (const float*)d_in[18];
    const float* b2_1 = (const float*)d_in[19];
    const float* lin_w= (const float*)d_in[20];
    const float* lin_b= (const float*)d_in[21];

    float* ws     = (float*)d_ws;
    float* aggr   = ws;                 // 6.4M floats (reused as x2 output of layer 2)
    float* t      = ws + 6400000;       // 6.4M
    float* x1     = ws + 12800000;      // 6.4M
    float* gsum   = ws + 19200000;      // 128
    float* gsq    = gsum + 128;         // 128
    float* scale  = gsq + 128;          // 128
    float* shift  = scale + 128;        // 128
    float* pooled = ws + 19200512;      // 512*128

    const size_t nbytesX = (size_t)N_NODES * C * sizeof(float);

    // ---- layer 1
    hipMemsetAsync(aggr, 0, nbytesX, stream);
    edge_kernel<<<N_EDGES / 4, 256, 0, stream>>>(x0, ei, ew, We0, be0, aggr);
    gemm_kernel<0><<<512, 256, 0, stream>>>(x0, aggr, W1_0, b1_0, nullptr, nullptr, t);
    hipMemsetAsync(gsum, 0, 256 * sizeof(float), stream);
    stats_kernel<<<256, 256, 0, stream>>>(t, gsum, gsq);
    bnfin_kernel<<<1, 128, 0, stream>>>(gsum, gsq, g0, bt0, scale, shift);
    gemm_kernel<1><<<512, 256, 0, stream>>>(t, nullptr, W2_0, b2_0, scale, shift, x1);

    // ---- layer 2
    hipMemsetAsync(aggr, 0, nbytesX, stream);
    edge_kernel<<<N_EDGES / 4, 256, 0, stream>>>(x1, ei, ew, We1, be1, aggr);
    gemm_kernel<0><<<512, 256, 0, stream>>>(x1, aggr, W1_1, b1_1, nullptr, nullptr, t);
    hipMemsetAsync(gsum, 0, 256 * sizeof(float), stream);
    stats_kernel<<<256, 256, 0, stream>>>(t, gsum, gsq);
    bnfin_kernel<<<1, 128, 0, stream>>>(gsum, gsq, g1, bt1, scale, shift);
    gemm_kernel<1><<<512, 256, 0, stream>>>(t, nullptr, W2_1, b2_1, scale, shift, aggr /* = x2 */);

    // ---- pool + final linear
    hipMemsetAsync(pooled, 0, (size_t)N_GRAPHS * C * sizeof(float), stream);
    pool_kernel<<<(N_NODES * C) / 256, 256, 0, stream>>>(aggr, batch, pooled);
    final_kernel<<<N_GRAPHS, 64, 0, stream>>>(pooled, lin_w, lin_b, (float*)d_out);
}

// Round 3
// 694.746 us; speedup vs baseline: 2.4294x; 2.4294x over previous
//
#include <hip/hip_runtime.h>

#define N_NODES 50000
#define N_EDGES 800000
#define C 128
#define N_GRAPHS 512
#define OUTDIM 5
#define BN_EPS 1e-5f

// ================= CSR build =================
__global__ __launch_bounds__(256) void hist_kernel(const int* __restrict__ ei,
                                                   int* __restrict__ deg)
{
    int e = blockIdx.x * 256 + threadIdx.x;     // grid covers N_EDGES exactly
    atomicAdd(&deg[ei[N_EDGES + e]], 1);
}

// single 1024-thread block exclusive scan over 50000 degrees -> rowptr, cursor
__global__ __launch_bounds__(1024) void scan_kernel(const int* __restrict__ deg,
                                                    int* __restrict__ rowptr,
                                                    int* __restrict__ cursor)
{
    __shared__ int part[1024];
    const int CH = 49;                           // 1024*49 = 50176 >= 50000
    int tid = threadIdx.x;
    int base = tid * CH;
    int s = 0;
    #pragma unroll
    for (int i = 0; i < CH; ++i) {
        int idx = base + i;
        if (idx < N_NODES) s += deg[idx];
    }
    part[tid] = s;
    __syncthreads();
    for (int off = 1; off < 1024; off <<= 1) {
        int v = (tid >= off) ? part[tid - off] : 0;
        __syncthreads();
        part[tid] += v;
        __syncthreads();
    }
    int run = (tid > 0) ? part[tid - 1] : 0;     // exclusive prefix of this chunk
    #pragma unroll
    for (int i = 0; i < CH; ++i) {
        int idx = base + i;
        if (idx < N_NODES) {
            rowptr[idx] = run;
            cursor[idx] = run;
            run += deg[idx];
        }
    }
    if (tid == 1023) rowptr[N_NODES] = run;      // = N_EDGES
}

// scatter packed {src, w} into CSR slots
__global__ __launch_bounds__(256) void scatter_kernel(const int* __restrict__ ei,
                                                      const float* __restrict__ ew,
                                                      int* __restrict__ cursor,
                                                      float2* __restrict__ csr)
{
    int e = blockIdx.x * 256 + threadIdx.x;
    int dst = ei[N_EDGES + e];
    int pos = atomicAdd(&cursor[dst], 1);
    float2 ent;
    ent.x = __int_as_float(ei[e]);   // src
    ent.y = ew[e];                   // weight
    csr[pos] = ent;
}

// ================= atomic-free aggregation =================
// one wave per node: h[node] = x[node] + sum_e relu(x[src_e] + w_e*We + be)
__global__ __launch_bounds__(256) void aggr_kernel(const float* __restrict__ x,
                                                   const float2* __restrict__ csr,
                                                   const int* __restrict__ rowptr,
                                                   const float* __restrict__ We,
                                                   const float* __restrict__ be,
                                                   float* __restrict__ hout)
{
    int node = blockIdx.x * 4 + (threadIdx.x >> 6);   // 12500 blocks cover 50000
    int lane = threadIdx.x & 63;
    int c = lane * 2;
    float2 wev = *reinterpret_cast<const float2*>(&We[c]);
    float2 bev = *reinterpret_cast<const float2*>(&be[c]);
    int p  = rowptr[node];
    int p1 = rowptr[node + 1];
    float2 acc = *reinterpret_cast<const float2*>(&x[(size_t)node * C + c]);
    // unroll-by-2 for load ILP
    for (; p + 2 <= p1; p += 2) {
        float2 e0 = csr[p], e1 = csr[p + 1];
        int s0 = __float_as_int(e0.x), s1 = __float_as_int(e1.x);
        float2 xa = *reinterpret_cast<const float2*>(&x[(size_t)s0 * C + c]);
        float2 xb = *reinterpret_cast<const float2*>(&x[(size_t)s1 * C + c]);
        float m;
        m = xa.x + e0.y * wev.x + bev.x; acc.x += fmaxf(m, 0.f);
        m = xa.y + e0.y * wev.y + bev.y; acc.y += fmaxf(m, 0.f);
        m = xb.x + e1.y * wev.x + bev.x; acc.x += fmaxf(m, 0.f);
        m = xb.y + e1.y * wev.y + bev.y; acc.y += fmaxf(m, 0.f);
    }
    if (p < p1) {
        float2 e0 = csr[p];
        int s0 = __float_as_int(e0.x);
        float2 xa = *reinterpret_cast<const float2*>(&x[(size_t)s0 * C + c]);
        float m;
        m = xa.x + e0.y * wev.x + bev.x; acc.x += fmaxf(m, 0.f);
        m = xa.y + e0.y * wev.y + bev.y; acc.y += fmaxf(m, 0.f);
    }
    *reinterpret_cast<float2*>(&hout[(size_t)node * C + c]) = acc;
}

// ================= 50000x128 @ 128x128^T GEMM, f32 vector ALU =================
// MODE 0: out = A@W.T + bias                                  (pre-BN "t")
// MODE 1: h = relu(A*scale + shift); out = relu(h@W.T + bias) (layer output)
template<int MODE>
__global__ __launch_bounds__(256) void gemm_kernel(
    const float* __restrict__ A,
    const float* __restrict__ W,          // [128][128] row-major [j][k]
    const float* __restrict__ bias,
    const float* __restrict__ scale, const float* __restrict__ shift,
    float* __restrict__ out)
{
    __shared__ __align__(16) float ws[128 * 132];  // W^T, padded rows: ws[k*132+j]
    __shared__ __align__(16) float hs[16 * 132];   // h tile, padded
    int tid = threadIdx.x;

    #pragma unroll 4
    for (int i = 0; i < 64; ++i) {
        int idx = tid + i * 256;
        int j = idx >> 7, k = idx & 127;
        ws[k * 132 + j] = W[idx];
    }

    int cg = tid & 15;
    int r  = tid >> 4;
    int c0 = cg * 4;

    float bia[8];
    #pragma unroll
    for (int i = 0; i < 4; ++i) { bia[i] = bias[c0 + i]; bia[4 + i] = bias[c0 + 64 + i]; }

    const int ntiles = N_NODES / 16;   // 3125 exact
    for (int tile = blockIdx.x; tile < ntiles; tile += gridDim.x) {
        int row0 = tile * 16;
        __syncthreads();
        #pragma unroll
        for (int i = 0; i < 8; ++i) {
            int idx = tid + i * 256;
            int rr = idx >> 7, cc = idx & 127;
            size_t gi = (size_t)(row0 + rr) * C + cc;
            float v;
            if (MODE == 0) {
                v = A[gi];
            } else {
                v = A[gi] * scale[cc] + shift[cc];
                v = v > 0.f ? v : 0.f;
            }
            hs[rr * 132 + cc] = v;
        }
        __syncthreads();

        float acc[8] = {0.f,0.f,0.f,0.f,0.f,0.f,0.f,0.f};
        #pragma unroll 4
        for (int k = 0; k < 128; k += 4) {
            float4 hv = *reinterpret_cast<const float4*>(&hs[r * 132 + k]);
            #pragma unroll
            for (int kk = 0; kk < 4; ++kk) {
                float h = (&hv.x)[kk];
                float4 w0 = *reinterpret_cast<const float4*>(&ws[(k + kk) * 132 + c0]);
                float4 w1 = *reinterpret_cast<const float4*>(&ws[(k + kk) * 132 + c0 + 64]);
                acc[0] += h * w0.x; acc[1] += h * w0.y; acc[2] += h * w0.z; acc[3] += h * w0.w;
                acc[4] += h * w1.x; acc[5] += h * w1.y; acc[6] += h * w1.z; acc[7] += h * w1.w;
            }
        }

        float4 o0, o1;
        o0.x = acc[0] + bia[0]; o0.y = acc[1] + bia[1]; o0.z = acc[2] + bia[2]; o0.w = acc[3] + bia[3];
        o1.x = acc[4] + bia[4]; o1.y = acc[5] + bia[5]; o1.z = acc[6] + bia[6]; o1.w = acc[7] + bia[7];
        if (MODE == 1) {
            o0.x = o0.x > 0.f ? o0.x : 0.f; o0.y = o0.y > 0.f ? o0.y : 0.f;
            o0.z = o0.z > 0.f ? o0.z : 0.f; o0.w = o0.w > 0.f ? o0.w : 0.f;
            o1.x = o1.x > 0.f ? o1.x : 0.f; o1.y = o1.y > 0.f ? o1.y : 0.f;
            o1.z = o1.z > 0.f ? o1.z : 0.f; o1.w = o1.w > 0.f ? o1.w : 0.f;
        }
        size_t ro = (size_t)(row0 + r) * C;
        *reinterpret_cast<float4*>(&out[ro + c0])      = o0;
        *reinterpret_cast<float4*>(&out[ro + c0 + 64]) = o1;
    }
}

// ================= BatchNorm stats =================
__global__ __launch_bounds__(256) void stats_kernel(const float* __restrict__ t,
                                                    float* __restrict__ gsum, float* __restrict__ gsq)
{
    int tid = threadIdx.x;
    int c = tid & 127;
    int half = tid >> 7;
    float s = 0.f, q = 0.f;
    for (int n = blockIdx.x * 2 + half; n < N_NODES; n += gridDim.x * 2) {
        float v = t[(size_t)n * C + c];
        s += v; q += v * v;
    }
    __shared__ float ls[256];
    ls[tid] = s; __syncthreads();
    if (tid < 128) unsafeAtomicAdd(&gsum[tid], ls[tid] + ls[tid + 128]);
    __syncthreads();
    ls[tid] = q; __syncthreads();
    if (tid < 128) unsafeAtomicAdd(&gsq[tid], ls[tid] + ls[tid + 128]);
}

__global__ void bnfin_kernel(const float* __restrict__ gsum, const float* __restrict__ gsq,
                             const float* __restrict__ g, const float* __restrict__ bt,
                             float* __restrict__ scale, float* __restrict__ shift)
{
    int c = threadIdx.x;
    float mu  = gsum[c] * (1.f / N_NODES);
    float var = gsq[c] * (1.f / N_NODES) - mu * mu;
    float rs  = rsqrtf(var + BN_EPS);
    float sc  = rs * g[c];
    scale[c] = sc;
    shift[c] = bt[c] - mu * sc;
}

// ================= segment_max pool =================
__global__ __launch_bounds__(256) void pool_kernel(const float* __restrict__ x,
                                                   const int* __restrict__ batch,
                                                   float* __restrict__ pooled)
{
    int idx = blockIdx.x * 256 + threadIdx.x;
    int n = idx >> 7, c = idx & 127;
    int g = batch[n];
    float v = x[idx];
    atomicMax(reinterpret_cast<int*>(&pooled[(size_t)g * C + c]), __float_as_int(v));
}

// ================= final linear =================
__global__ __launch_bounds__(64) void final_kernel(const float* __restrict__ pooled,
                                                   const float* __restrict__ lw,
                                                   const float* __restrict__ lb,
                                                   float* __restrict__ out)
{
    int gph = blockIdx.x;
    int lane = threadIdx.x;
    float v0 = pooled[(size_t)gph * C + lane];
    float v1 = pooled[(size_t)gph * C + lane + 64];
    for (int o = 0; o < OUTDIM; ++o) {
        float p = v0 * lw[o * C + lane] + v1 * lw[o * C + lane + 64];
        #pragma unroll
        for (int off = 32; off > 0; off >>= 1) p += __shfl_down(p, off);
        if (lane == 0) out[gph * OUTDIM + o] = p + lb[o];
    }
}

extern "C" void kernel_launch(void* const* d_in, const int* in_sizes, int n_in,
                              void* d_out, int out_size, void* d_ws, size_t ws_size,
                              hipStream_t stream)
{
    const float* x0   = (const float*)d_in[0];
    const int*   ei   = (const int*)  d_in[1];
    const float* ew   = (const float*)d_in[2];
    const int*   batch= (const int*)  d_in[3];
    const float* We0  = (const float*)d_in[4];
    const float* be0  = (const float*)d_in[5];
    const float* W1_0 = (const float*)d_in[6];
    const float* b1_0 = (const float*)d_in[7];
    const float* g0   = (const float*)d_in[8];
    const float* bt0  = (const float*)d_in[9];
    const float* W2_0 = (const float*)d_in[10];
    const float* b2_0 = (const float*)d_in[11];
    const float* We1  = (const float*)d_in[12];
    const float* be1  = (const float*)d_in[13];
    const float* W1_1 = (const float*)d_in[14];
    const float* b1_1 = (const float*)d_in[15];
    const float* g1   = (const float*)d_in[16];
    const float* bt1  = (const float*)d_in[17];
    const float* W2_1 = (const float*)d_in[18];
    const float* b2_1 = (const float*)d_in[19];
    const float* lin_w= (const float*)d_in[20];
    const float* lin_b= (const float*)d_in[21];

    float* ws = (float*)d_ws;
    float*  bufA  = ws;                       // h1 / h2      (6.4M floats)
    float*  bufB  = ws + 6400000;             // t1 / t2      (6.4M)
    float*  bufC  = ws + 12800000;            // x1 / x2      (6.4M)
    float2* csr   = (float2*)(ws + 19200000); // 800K float2  (1.6M floats)
    int*    ibase = (int*)(ws + 20800000);
    int*    deg    = ibase;                   // 50000
    int*    rowptr = ibase + 50000;           // 50001
    int*    cursor = ibase + 100001;          // 50000
    float*  gsum   = ws + 20960000;           // 128
    float*  gsq    = gsum + 128;
    float*  scale  = gsq + 128;
    float*  shift  = scale + 128;
    float*  pooled = ws + 20960512;           // 512*128

    // ---- build CSR once (shared by both layers)
    hipMemsetAsync(deg, 0, N_NODES * sizeof(int), stream);
    hist_kernel<<<N_EDGES / 256, 256, 0, stream>>>(ei, deg);
    scan_kernel<<<1, 1024, 0, stream>>>(deg, rowptr, cursor);
    scatter_kernel<<<N_EDGES / 256, 256, 0, stream>>>(ei, ew, cursor, csr);

    // ---- layer 1
    aggr_kernel<<<N_NODES / 4, 256, 0, stream>>>(x0, csr, rowptr, We0, be0, bufA);
    gemm_kernel<0><<<512, 256, 0, stream>>>(bufA, W1_0, b1_0, nullptr, nullptr, bufB);
    hipMemsetAsync(gsum, 0, 256 * sizeof(float), stream);
    stats_kernel<<<256, 256, 0, stream>>>(bufB, gsum, gsq);
    bnfin_kernel<<<1, 128, 0, stream>>>(gsum, gsq, g0, bt0, scale, shift);
    gemm_kernel<1><<<512, 256, 0, stream>>>(bufB, W2_0, b2_0, scale, shift, bufC);

    // ---- layer 2
    aggr_kernel<<<N_NODES / 4, 256, 0, stream>>>(bufC, csr, rowptr, We1, be1, bufA);
    gemm_kernel<0><<<512, 256, 0, stream>>>(bufA, W1_1, b1_1, nullptr, nullptr, bufB);
    hipMemsetAsync(gsum, 0, 256 * sizeof(float), stream);
    stats_kernel<<<256, 256, 0, stream>>>(bufB, gsum, gsq);
    bnfin_kernel<<<1, 128, 0, stream>>>(gsum, gsq, g1, bt1, scale, shift);
    gemm_kernel<1><<<512, 256, 0, stream>>>(bufB, W2_1, b2_1, scale, shift, bufA /* x2 */);

    // ---- pool + final linear
    hipMemsetAsync(pooled, 0, (size_t)N_GRAPHS * C * sizeof(float), stream);
    pool_kernel<<<(N_NODES * C) / 256, 256, 0, stream>>>(bufA, batch, pooled);
    final_kernel<<<N_GRAPHS, 64, 0, stream>>>(pooled, lin_w, lin_b, (float*)d_out);
}

// Round 4
// 577.593 us; speedup vs baseline: 2.9222x; 1.2028x over previous
//
#include <hip/hip_runtime.h>

#define N_NODES 50000
#define N_EDGES 800000
#define C 128
#define N_GRAPHS 512
#define OUTDIM 5
#define BN_EPS 1e-5f
#define NB_SCAN 196   // ceil(50000/256)

// ================= CSR build =================
__global__ __launch_bounds__(256) void hist_kernel(const int* __restrict__ ei,
                                                   int* __restrict__ deg)
{
    int e = blockIdx.x * 256 + threadIdx.x;     // grid covers N_EDGES exactly
    atomicAdd(&deg[ei[N_EDGES + e]], 1);
}

// pass 1: per-block exclusive scan of deg -> rowptr(local), block totals -> bsum
__global__ __launch_bounds__(256) void scan1_kernel(const int* __restrict__ deg,
                                                    int* __restrict__ rowptr,
                                                    int* __restrict__ bsum)
{
    __shared__ int sh[256];
    int tid = threadIdx.x;
    int i = blockIdx.x * 256 + tid;
    int v = (i < N_NODES) ? deg[i] : 0;
    sh[tid] = v;
    __syncthreads();
    #pragma unroll
    for (int off = 1; off < 256; off <<= 1) {
        int t = (tid >= off) ? sh[tid - off] : 0;
        __syncthreads();
        sh[tid] += t;
        __syncthreads();
    }
    if (i < N_NODES) rowptr[i] = sh[tid] - v;      // exclusive within block
    if (tid == 255) bsum[blockIdx.x] = sh[255];
}

// pass 2: single small block scans the 196 block sums (exclusive, in place)
__global__ __launch_bounds__(256) void scan2_kernel(int* __restrict__ bsum)
{
    __shared__ int sh[256];
    int tid = threadIdx.x;
    int v = (tid < NB_SCAN) ? bsum[tid] : 0;
    sh[tid] = v;
    __syncthreads();
    #pragma unroll
    for (int off = 1; off < 256; off <<= 1) {
        int t = (tid >= off) ? sh[tid - off] : 0;
        __syncthreads();
        sh[tid] += t;
        __syncthreads();
    }
    if (tid < NB_SCAN) bsum[tid] = sh[tid] - v;    // exclusive
}

// pass 3: add block base, emit rowptr + cursor
__global__ __launch_bounds__(256) void scan3_kernel(const int* __restrict__ bsum,
                                                    int* __restrict__ rowptr,
                                                    int* __restrict__ cursor)
{
    int i = blockIdx.x * 256 + threadIdx.x;
    if (i < N_NODES) {
        int v = rowptr[i] + bsum[blockIdx.x];
        rowptr[i] = v;
        cursor[i] = v;
    }
    if (i == 0) rowptr[N_NODES] = N_EDGES;         // total degree is exact
}

// scatter packed {src, w} into CSR slots
__global__ __launch_bounds__(256) void scatter_kernel(const int* __restrict__ ei,
                                                      const float* __restrict__ ew,
                                                      int* __restrict__ cursor,
                                                      float2* __restrict__ csr)
{
    int e = blockIdx.x * 256 + threadIdx.x;
    int dst = ei[N_EDGES + e];
    int pos = atomicAdd(&cursor[dst], 1);
    float2 ent;
    ent.x = __int_as_float(ei[e]);   // src
    ent.y = ew[e];                   // weight
    csr[pos] = ent;
}

// ================= atomic-free aggregation =================
// one wave per node: h[node] = x[node] + sum_e relu(x[src_e] + w_e*We + be)
__global__ __launch_bounds__(256) void aggr_kernel(const float* __restrict__ x,
                                                   const float2* __restrict__ csr,
                                                   const int* __restrict__ rowptr,
                                                   const float* __restrict__ We,
                                                   const float* __restrict__ be,
                                                   float* __restrict__ hout)
{
    int node = blockIdx.x * 4 + (threadIdx.x >> 6);   // 12500 blocks cover 50000
    int lane = threadIdx.x & 63;
    int c = lane * 2;
    float2 wev = *reinterpret_cast<const float2*>(&We[c]);
    float2 bev = *reinterpret_cast<const float2*>(&be[c]);
    int p  = rowptr[node];
    int p1 = rowptr[node + 1];
    float2 acc = *reinterpret_cast<const float2*>(&x[(size_t)node * C + c]);
    for (; p + 2 <= p1; p += 2) {
        float2 e0 = csr[p], e1 = csr[p + 1];
        int s0 = __float_as_int(e0.x), s1 = __float_as_int(e1.x);
        float2 xa = *reinterpret_cast<const float2*>(&x[(size_t)s0 * C + c]);
        float2 xb = *reinterpret_cast<const float2*>(&x[(size_t)s1 * C + c]);
        float m;
        m = xa.x + e0.y * wev.x + bev.x; acc.x += fmaxf(m, 0.f);
        m = xa.y + e0.y * wev.y + bev.y; acc.y += fmaxf(m, 0.f);
        m = xb.x + e1.y * wev.x + bev.x; acc.x += fmaxf(m, 0.f);
        m = xb.y + e1.y * wev.y + bev.y; acc.y += fmaxf(m, 0.f);
    }
    if (p < p1) {
        float2 e0 = csr[p];
        int s0 = __float_as_int(e0.x);
        float2 xa = *reinterpret_cast<const float2*>(&x[(size_t)s0 * C + c]);
        float m;
        m = xa.x + e0.y * wev.x + bev.x; acc.x += fmaxf(m, 0.f);
        m = xa.y + e0.y * wev.y + bev.y; acc.y += fmaxf(m, 0.f);
    }
    *reinterpret_cast<float2*>(&hout[(size_t)node * C + c]) = acc;
}

// ================= 50000x128 @ 128x128^T GEMM, f32 vector ALU =================
// MODE 0: out = A@W.T + bias                                  (pre-BN "t")
// MODE 1: h = relu(A*scale + shift); out = relu(h@W.T + bias) (layer output)
template<int MODE>
__global__ __launch_bounds__(256) void gemm_kernel(
    const float* __restrict__ A,
    const float* __restrict__ W,          // [128][128] row-major [j][k]
    const float* __restrict__ bias,
    const float* __restrict__ scale, const float* __restrict__ shift,
    float* __restrict__ out)
{
    __shared__ __align__(16) float ws[128 * 132];  // W^T, padded rows: ws[k*132+j]
    __shared__ __align__(16) float hs[16 * 132];   // h tile, padded
    int tid = threadIdx.x;

    #pragma unroll 4
    for (int i = 0; i < 64; ++i) {
        int idx = tid + i * 256;
        int j = idx >> 7, k = idx & 127;
        ws[k * 132 + j] = W[idx];
    }

    int cg = tid & 15;
    int r  = tid >> 4;
    int c0 = cg * 4;

    float bia[8];
    #pragma unroll
    for (int i = 0; i < 4; ++i) { bia[i] = bias[c0 + i]; bia[4 + i] = bias[c0 + 64 + i]; }

    const int ntiles = N_NODES / 16;   // 3125 exact
    for (int tile = blockIdx.x; tile < ntiles; tile += gridDim.x) {
        int row0 = tile * 16;
        __syncthreads();
        #pragma unroll
        for (int i = 0; i < 8; ++i) {
            int idx = tid + i * 256;
            int rr = idx >> 7, cc = idx & 127;
            size_t gi = (size_t)(row0 + rr) * C + cc;
            float v;
            if (MODE == 0) {
                v = A[gi];
            } else {
                v = A[gi] * scale[cc] + shift[cc];
                v = v > 0.f ? v : 0.f;
            }
            hs[rr * 132 + cc] = v;
        }
        __syncthreads();

        float acc[8] = {0.f,0.f,0.f,0.f,0.f,0.f,0.f,0.f};
        #pragma unroll 4
        for (int k = 0; k < 128; k += 4) {
            float4 hv = *reinterpret_cast<const float4*>(&hs[r * 132 + k]);
            #pragma unroll
            for (int kk = 0; kk < 4; ++kk) {
                float h = (&hv.x)[kk];
                float4 w0 = *reinterpret_cast<const float4*>(&ws[(k + kk) * 132 + c0]);
                float4 w1 = *reinterpret_cast<const float4*>(&ws[(k + kk) * 132 + c0 + 64]);
                acc[0] += h * w0.x; acc[1] += h * w0.y; acc[2] += h * w0.z; acc[3] += h * w0.w;
                acc[4] += h * w1.x; acc[5] += h * w1.y; acc[6] += h * w1.z; acc[7] += h * w1.w;
            }
        }

        float4 o0, o1;
        o0.x = acc[0] + bia[0]; o0.y = acc[1] + bia[1]; o0.z = acc[2] + bia[2]; o0.w = acc[3] + bia[3];
        o1.x = acc[4] + bia[4]; o1.y = acc[5] + bia[5]; o1.z = acc[6] + bia[6]; o1.w = acc[7] + bia[7];
        if (MODE == 1) {
            o0.x = o0.x > 0.f ? o0.x : 0.f; o0.y = o0.y > 0.f ? o0.y : 0.f;
            o0.z = o0.z > 0.f ? o0.z : 0.f; o0.w = o0.w > 0.f ? o0.w : 0.f;
            o1.x = o1.x > 0.f ? o1.x : 0.f; o1.y = o1.y > 0.f ? o1.y : 0.f;
            o1.z = o1.z > 0.f ? o1.z : 0.f; o1.w = o1.w > 0.f ? o1.w : 0.f;
        }
        size_t ro = (size_t)(row0 + r) * C;
        *reinterpret_cast<float4*>(&out[ro + c0])      = o0;
        *reinterpret_cast<float4*>(&out[ro + c0 + 64]) = o1;
    }
}

// ================= BatchNorm stats =================
__global__ __launch_bounds__(256) void stats_kernel(const float* __restrict__ t,
                                                    float* __restrict__ gsum, float* __restrict__ gsq)
{
    int tid = threadIdx.x;
    int c = tid & 127;
    int half = tid >> 7;
    float s = 0.f, q = 0.f;
    for (int n = blockIdx.x * 2 + half; n < N_NODES; n += gridDim.x * 2) {
        float v = t[(size_t)n * C + c];
        s += v; q += v * v;
    }
    __shared__ float ls[256];
    ls[tid] = s; __syncthreads();
    if (tid < 128) unsafeAtomicAdd(&gsum[tid], ls[tid] + ls[tid + 128]);
    __syncthreads();
    ls[tid] = q; __syncthreads();
    if (tid < 128) unsafeAtomicAdd(&gsq[tid], ls[tid] + ls[tid + 128]);
}

__global__ void bnfin_kernel(const float* __restrict__ gsum, const float* __restrict__ gsq,
                             const float* __restrict__ g, const float* __restrict__ bt,
                             float* __restrict__ scale, float* __restrict__ shift)
{
    int c = threadIdx.x;
    float mu  = gsum[c] * (1.f / N_NODES);
    float var = gsq[c] * (1.f / N_NODES) - mu * mu;
    float rs  = rsqrtf(var + BN_EPS);
    float sc  = rs * g[c];
    scale[c] = sc;
    shift[c] = bt[c] - mu * sc;
}

// ================= segment_max pool =================
__global__ __launch_bounds__(256) void pool_kernel(const float* __restrict__ x,
                                                   const int* __restrict__ batch,
                                                   float* __restrict__ pooled)
{
    int idx = blockIdx.x * 256 + threadIdx.x;
    int n = idx >> 7, c = idx & 127;
    int g = batch[n];
    float v = x[idx];
    atomicMax(reinterpret_cast<int*>(&pooled[(size_t)g * C + c]), __float_as_int(v));
}

// ================= final linear =================
__global__ __launch_bounds__(64) void final_kernel(const float* __restrict__ pooled,
                                                   const float* __restrict__ lw,
                                                   const float* __restrict__ lb,
                                                   float* __restrict__ out)
{
    int gph = blockIdx.x;
    int lane = threadIdx.x;
    float v0 = pooled[(size_t)gph * C + lane];
    float v1 = pooled[(size_t)gph * C + lane + 64];
    for (int o = 0; o < OUTDIM; ++o) {
        float p = v0 * lw[o * C + lane] + v1 * lw[o * C + lane + 64];
        #pragma unroll
        for (int off = 32; off > 0; off >>= 1) p += __shfl_down(p, off);
        if (lane == 0) out[gph * OUTDIM + o] = p + lb[o];
    }
}

extern "C" void kernel_launch(void* const* d_in, const int* in_sizes, int n_in,
                              void* d_out, int out_size, void* d_ws, size_t ws_size,
                              hipStream_t stream)
{
    const float* x0   = (const float*)d_in[0];
    const int*   ei   = (const int*)  d_in[1];
    const float* ew   = (const float*)d_in[2];
    const int*   batch= (const int*)  d_in[3];
    const float* We0  = (const float*)d_in[4];
    const float* be0  = (const float*)d_in[5];
    const float* W1_0 = (const float*)d_in[6];
    const float* b1_0 = (const float*)d_in[7];
    const float* g0   = (const float*)d_in[8];
    const float* bt0  = (const float*)d_in[9];
    const float* W2_0 = (const float*)d_in[10];
    const float* b2_0 = (const float*)d_in[11];
    const float* We1  = (const float*)d_in[12];
    const float* be1  = (const float*)d_in[13];
    const float* W1_1 = (const float*)d_in[14];
    const float* b1_1 = (const float*)d_in[15];
    const float* g1   = (const float*)d_in[16];
    const float* bt1  = (const float*)d_in[17];
    const float* W2_1 = (const float*)d_in[18];
    const float* b2_1 = (const float*)d_in[19];
    const float* lin_w= (const float*)d_in[20];
    const float* lin_b= (const float*)d_in[21];

    float* ws = (float*)d_ws;
    float*  bufA  = ws;                       // h1 / h2      (6.4M floats)
    float*  bufB  = ws + 6400000;             // t1 / t2      (6.4M)
    float*  bufC  = ws + 12800000;            // x1 / x2      (6.4M)
    float2* csr   = (float2*)(ws + 19200000); // 800K float2  (1.6M floats)
    int*    ibase = (int*)(ws + 20800000);
    int*    deg    = ibase;                   // 50000
    int*    rowptr = ibase + 50000;           // 50001
    int*    cursor = ibase + 100001;          // 50000
    int*    bsum   = ibase + 150001;          // 196 (+pad)
    float*  gsum   = ws + 20960000;           // 128
    float*  gsq    = gsum + 128;
    float*  scale  = gsq + 128;
    float*  shift  = scale + 128;
    float*  pooled = ws + 20960512;           // 512*128

    // ---- build CSR once (shared by both layers)
    hipMemsetAsync(deg, 0, N_NODES * sizeof(int), stream);
    hist_kernel<<<N_EDGES / 256, 256, 0, stream>>>(ei, deg);
    scan1_kernel<<<NB_SCAN, 256, 0, stream>>>(deg, rowptr, bsum);
    scan2_kernel<<<1, 256, 0, stream>>>(bsum);
    scan3_kernel<<<NB_SCAN, 256, 0, stream>>>(bsum, rowptr, cursor);
    scatter_kernel<<<N_EDGES / 256, 256, 0, stream>>>(ei, ew, cursor, csr);

    // ---- layer 1
    aggr_kernel<<<N_NODES / 4, 256, 0, stream>>>(x0, csr, rowptr, We0, be0, bufA);
    gemm_kernel<0><<<512, 256, 0, stream>>>(bufA, W1_0, b1_0, nullptr, nullptr, bufB);
    hipMemsetAsync(gsum, 0, 256 * sizeof(float), stream);
    stats_kernel<<<256, 256, 0, stream>>>(bufB, gsum, gsq);
    bnfin_kernel<<<1, 128, 0, stream>>>(gsum, gsq, g0, bt0, scale, shift);
    gemm_kernel<1><<<512, 256, 0, stream>>>(bufB, W2_0, b2_0, scale, shift, bufC);

    // ---- layer 2
    aggr_kernel<<<N_NODES / 4, 256, 0, stream>>>(bufC, csr, rowptr, We1, be1, bufA);
    gemm_kernel<0><<<512, 256, 0, stream>>>(bufA, W1_1, b1_1, nullptr, nullptr, bufB);
    hipMemsetAsync(gsum, 0, 256 * sizeof(float), stream);
    stats_kernel<<<256, 256, 0, stream>>>(bufB, gsum, gsq);
    bnfin_kernel<<<1, 128, 0, stream>>>(gsum, gsq, g1, bt1, scale, shift);
    gemm_kernel<1><<<512, 256, 0, stream>>>(bufB, W2_1, b2_1, scale, shift, bufA /* x2 */);

    // ---- pool + final linear
    hipMemsetAsync(pooled, 0, (size_t)N_GRAPHS * C * sizeof(float), stream);
    pool_kernel<<<(N_NODES * C) / 256, 256, 0, stream>>>(bufA, batch, pooled);
    final_kernel<<<N_GRAPHS, 64, 0, stream>>>(pooled, lin_w, lin_b, (float*)d_out);
}